// Round 11
// baseline (136.282 us; speedup 1.0000x reference)
//
#include <hip/hip_runtime.h>
#include <cmath>

#define B_ 2
#define X_ 128
#define Y_ 128
#define Z_ 128
#define C_ 8
#define ZC 1024         // Z_*C_
#define XS 131072       // Y_*ZC, stride of x in elements
#define BS 16777216     // X_*XS, stride of batch in elements
#define PF4 32768       // float4s per (b,x) plane
#define KTAPS 13
#define TAIL 6

struct Taps { float k[KTAPS]; };

__device__ __forceinline__ float4 ld4(const float* p) {
    return *reinterpret_cast<const float4*>(p);
}
__device__ __forceinline__ void st4(float* p, const float4& v) {
    *reinterpret_cast<float4*>(p) = v;
}
__device__ __forceinline__ float4 f4zero() { return make_float4(0.f, 0.f, 0.f, 0.f); }
__device__ __forceinline__ void fma4(float4& a, float s, const float4& b) {
    a.x = fmaf(s, b.x, a.x); a.y = fmaf(s, b.y, a.y);
    a.z = fmaf(s, b.z, a.z); a.w = fmaf(s, b.w, a.w);
}

// ---------------- Pass 1: Y conv, grid-strided COMPACT-FOOTPRINT gather ------
// R1-R10 evidence: every cold-read pass capped at 2.5-2.9 TB/s regardless of
// per-wave structure (occupancy 57%, MLP 28, 8KB visits, barrier-free stream
// all neutral), while warm-read and write-only traffic runs 5-7 TB/s. Theory:
// per-block private-region walks scatter ~1000 4KB fronts across 268 MB, so
// each HBM channel interleaves 256B pieces of ~1000 unrelated DRAM rows
// (row-thrash + imbalance). A grid-stride copy is fast because its
// INSTANTANEOUS chip-wide footprint is one compact window marching through
// memory. This kernel restores that property for the conv: chunk g = 8
// consecutive y-rows of one plane; concurrent blocks take adjacent g ->
// compact ~32MB band (reads AND writes) marching through the volume.
// Adjacent-chunk overlap reads (2.5x amplification) are L2/L3 hits inside
// the band. MLP=20/wave via pinned burst.
template <int T, int GRID>
__global__ __launch_bounds__(256, 1) void ygather(const float* __restrict__ src,
                                                  float* __restrict__ dst,
                                                  Taps tp) {
    const int t  = threadIdx.x;
    const int zc = t << 2;                         // word offset in 4KB row
    const int NCH = B_ * X_ * (Y_ / T);            // 4096 chunks

    for (int g = blockIdx.x; g < NCH; g += GRID) {
        const int p  = g >> 4;                     // plane = b*128+x  (Y_/T=16)
        const int y0 = (g & 15) * T;
        const float* sp = src + (size_t)p * XS + zc;
        float*       dp = dst + (size_t)p * XS + zc;

        float4 v[T + 2 * TAIL];
#pragma unroll
        for (int i = 0; i < T + 2 * TAIL; ++i) {
            const int yy = y0 - TAIL + i;
            v[i] = (yy >= 0 && yy < Y_) ? ld4(sp + yy * ZC) : f4zero();
        }
        // Pin the whole 20-row burst live, then fence the scheduler so no FMA
        // is hoisted into the burst (R5/R9 lesson: "memory" clobbers and
        // partial fences don't do this).
#pragma unroll
        for (int i = 0; i < T + 2 * TAIL; ++i) {
            asm volatile("" : "+v"(v[i].x), "+v"(v[i].y), "+v"(v[i].z), "+v"(v[i].w));
        }
        __builtin_amdgcn_sched_barrier(0);

#pragma unroll
        for (int j = 0; j < T; ++j) {
            float4 acc = f4zero();
#pragma unroll
            for (int i = 0; i < KTAPS; ++i) fma4(acc, tp.k[i], v[j + i]);
            st4(dp + (y0 + j) * ZC, acc);
        }
    }
}

// ------------- Pass 2: X-conv gather (L3-warm) + Z-conv via LDS row ----------
// Measured ~33-36us (R8/R10). Block = one zc row at (b,y), x-window W=16;
// pinned 28-plane burst; per-x LDS row staging for Z; lgkmcnt-only barrier
// (no vmcnt drain).
template <int W, bool DOZ>
__global__ __launch_bounds__(256, 1) void xzconv(const float* __restrict__ src,
                                                 float* __restrict__ dst,
                                                 Taps tp) {
    __shared__ float row[2][ZC];

    const int t   = threadIdx.x;
    const int gid = blockIdx.x;
    const int y   = (Y_ - 1) - (gid & (Y_ - 1));   // reversed: hit last-written tmp
    const int xw  = (gid >> 7) & (X_ / W - 1);
    const int b   = gid >> 10;

    const int x0   = xw * W;
    const int base = b * BS + y * ZC + (t << 2);   // this thread's f4 at plane x=0
    const int z    = t >> 1;
    const int cw   = (t & 1) << 2;

    float4 v[W + 2 * TAIL];
#pragma unroll
    for (int i = 0; i < W + 2 * TAIL; ++i) {
        const int xx = x0 - TAIL + i;
        v[i] = (xx >= 0 && xx < X_) ? ld4(src + base + xx * XS) : f4zero();
    }
#pragma unroll
    for (int i = 0; i < W + 2 * TAIL; ++i) {
        asm volatile("" : "+v"(v[i].x), "+v"(v[i].y), "+v"(v[i].z), "+v"(v[i].w));
    }
    __builtin_amdgcn_sched_barrier(0);

    int pp = 0;
#pragma unroll
    for (int j = 0; j < W; ++j) {
        float4 acc = f4zero();
#pragma unroll
        for (int i = 0; i < KTAPS; ++i) fma4(acc, tp.k[i], v[j + i]);

        if (DOZ) {
            st4(&row[pp][t << 2], acc);
            asm volatile("s_waitcnt lgkmcnt(0)" ::: "memory");
            __builtin_amdgcn_s_barrier();
            __builtin_amdgcn_sched_barrier(0);

            float4 zacc = f4zero();
#pragma unroll
            for (int i = 0; i < KTAPS; ++i) {
                const int zz = z - TAIL + i;
                if (zz >= 0 && zz < Z_) {
                    fma4(zacc, tp.k[i], ld4(&row[pp][(zz << 3) + cw]));
                }
            }
            st4(dst + base + (x0 + j) * XS, zacc);
            pp ^= 1;
        } else {
            st4(dst + base + (x0 + j) * XS, acc);
        }
    }
}

// -------- Fallback-only: fused Y+Z, single plane per block, in-place-safe ----
template <int SEGY, int P>
__global__ __launch_bounds__(256) void yzconv_kernel(const float* __restrict__ src,
                                                     float* __restrict__ dst,
                                                     Taps tp) {
    __shared__ float row[2][ZC];

    const int t    = threadIdx.x;
    const int s    = blockIdx.x % SEGY;
    const int rest = blockIdx.x / SEGY;
    const int x    = rest & (X_ - 1);
    const int b    = rest >> 7;

    const int pbase = b * BS + x * XS;
    const int zc    = t << 2;
    const int z     = t >> 1;
    const int cw    = (t & 1) << 2;

    const int ylen = Y_ / SEGY;
    const int y0   = s * ylen;

    auto ldrow = [&](int yy) -> float4 {
        return (yy >= 0 && yy < Y_) ? ld4(src + pbase + yy * ZC + zc) : f4zero();
    };

    float4 w[KTAPS];
#pragma unroll
    for (int i = 0; i < KTAPS - 1; ++i) w[i] = ldrow(y0 - TAIL + i);
    float4 pf[P];
#pragma unroll
    for (int i = 0; i < P; ++i) pf[i] = ldrow(y0 + TAIL + i);

    int p = 0;
    for (int yy = 0; yy < ylen; yy += P) {
#pragma unroll
        for (int k = 0; k < P; ++k) {
            const int y = y0 + yy + k;
            w[KTAPS - 1] = pf[k];
            pf[k] = ldrow(y + TAIL + P);

            float4 acc = f4zero();
#pragma unroll
            for (int i = 0; i < KTAPS; ++i) fma4(acc, tp.k[i], w[i]);
            st4(&row[p][zc], acc);
            asm volatile("s_waitcnt lgkmcnt(0)" ::: "memory");
            __builtin_amdgcn_s_barrier();
            __builtin_amdgcn_sched_barrier(0);

            float4 zacc = f4zero();
#pragma unroll
            for (int i = 0; i < KTAPS; ++i) {
                const int zz = z - TAIL + i;
                if (zz >= 0 && zz < Z_) {
                    fma4(zacc, tp.k[i], ld4(&row[p][(zz << 3) + cw]));
                }
            }
            st4(dst + pbase + y * ZC + zc, zacc);

#pragma unroll
            for (int i = 0; i < KTAPS - 1; ++i) w[i] = w[i + 1];
            p ^= 1;
        }
    }
}

extern "C" void kernel_launch(void* const* d_in, const int* in_sizes, int n_in,
                              void* d_out, int out_size, void* d_ws, size_t ws_size,
                              hipStream_t stream) {
    const float* in = (const float*)d_in[0];
    float* out = (float*)d_out;

    // Gaussian taps: tail = int(2.0*3.0 + 0.5) = 6, K = 13, sigma = 2
    Taps tp;
    {
        float kv[KTAPS];
        float sum = 0.f;
        for (int i = 0; i < KTAPS; ++i) {
            const float xx = (float)(i - TAIL);
            kv[i] = expf(-0.5f * xx * xx / 4.0f);
            sum += kv[i];
        }
        for (int i = 0; i < KTAPS; ++i) tp.k[i] = kv[i] / sum;
    }

    const size_t need_bytes = (size_t)B_ * BS * sizeof(float);  // 134 MB
    const bool use_ws = (ws_size >= need_bytes) && (d_ws != nullptr);
    float* tmp = use_ws ? (float*)d_ws : out;

    if (use_ws) {
        // Pass 1: compact-footprint Y conv, in (cold) -> tmp.
        // 1024 resident blocks x 4 grid-stride steps over 4096 chunks.
        ygather<8, 1024><<<1024, 256, 0, stream>>>(in, tmp, tp);
        // Pass 2: X gather (tmp L3-warm) + Z via LDS -> out. 2048 blocks.
        xzconv<16, true><<<B_ * (X_ / 16) * Y_, 256, 0, stream>>>(tmp, out, tp);
    } else {
        // Fallback (never expected): X-only gather in->out, then in-place
        // fused Y+Z per plane (block-local, writes trail reads).
        xzconv<16, false><<<B_ * (X_ / 16) * Y_, 256, 0, stream>>>(in, out, tp);
        yzconv_kernel<1, 4><<<B_ * X_, 256, 0, stream>>>(out, out, tp);
    }
}

// Round 12
// 118.228 us; speedup vs baseline: 1.1527x; 1.1527x over previous
//
#include <hip/hip_runtime.h>
#include <cmath>

#define B_ 2
#define X_ 128
#define Y_ 128
#define Z_ 128
#define C_ 8
#define ZC 1024         // Z_*C_
#define XS 131072       // Y_*ZC, stride of x in elements
#define BS 16777216     // X_*XS, stride of batch in elements
#define KTAPS 13
#define TAIL 6

struct Taps { float k[KTAPS]; };

__device__ __forceinline__ float4 ld4(const float* p) {
    return *reinterpret_cast<const float4*>(p);
}
__device__ __forceinline__ void st4(float* p, const float4& v) {
    *reinterpret_cast<float4*>(p) = v;
}
__device__ __forceinline__ float4 f4zero() { return make_float4(0.f, 0.f, 0.f, 0.f); }
__device__ __forceinline__ void fma4(float4& a, float s, const float4& b) {
    a.x = fmaf(s, b.x, a.x); a.y = fmaf(s, b.y, a.y);
    a.z = fmaf(s, b.z, a.z); a.w = fmaf(s, b.w, a.w);
}

// ---------------- Pass 1: Y conv, XCD-chunked compact bands ------------------
// R11 analysis: waves idle ~97% on memory backpressure; compact marching band
// raised BW 2.65->3.5 TB/s, so chip-wide delivery order/placement is the live
// variable. Remaining defect: default round-robin block->XCD assignment puts
// ADJACENT chunks (sharing 12 halo rows) on DIFFERENT XCDs -> halo re-reads
// miss the private L2, and each XCD's DRAM stream is 8-way diluted.
// Fix (T1, chunked): xcd = bid&7 owns the contiguous chunk range
// [xcd*256, (xcd+1)*256): resident blocks of one XCD march through a private
// ~17MB sequential slice; halo overlap = same-XCD L2 hit. T=16 cuts
// amplification to 28/16 = 1.75x.
template <int T>
__global__ __launch_bounds__(256, 1) void ygather(const float* __restrict__ src,
                                                  float* __restrict__ dst,
                                                  Taps tp) {
    const int t  = threadIdx.x;
    const int zc = t << 2;                          // word offset in 4KB row
    // NCH = B*X*(Y/T) = 2048 chunks; 2048 blocks; bijective XCD-chunked map.
    const int g  = (blockIdx.x & 7) * 256 + (blockIdx.x >> 3);
    const int p  = g >> 3;                          // plane index (Y_/T = 8)
    const int y0 = (g & 7) * T;

    const float* sp = src + (size_t)p * XS + zc;
    float*       dp = dst + (size_t)p * XS + zc;

    float4 v[T + 2 * TAIL];
#pragma unroll
    for (int i = 0; i < T + 2 * TAIL; ++i) {
        const int yy = y0 - TAIL + i;
        v[i] = (yy >= 0 && yy < Y_) ? ld4(sp + yy * ZC) : f4zero();
    }
    // Pin the 28-row burst live; fence so no FMA is hoisted into the burst.
#pragma unroll
    for (int i = 0; i < T + 2 * TAIL; ++i) {
        asm volatile("" : "+v"(v[i].x), "+v"(v[i].y), "+v"(v[i].z), "+v"(v[i].w));
    }
    __builtin_amdgcn_sched_barrier(0);

#pragma unroll
    for (int j = 0; j < T; ++j) {
        float4 acc = f4zero();
#pragma unroll
        for (int i = 0; i < KTAPS; ++i) fma4(acc, tp.k[i], v[j + i]);
        st4(dp + (y0 + j) * ZC, acc);
    }
}

// ------------- Pass 2: X-conv gather (L3-warm) + Z-conv via LDS row ----------
// Measured 33-36us in R8/R10 (L3-warm src). Block = one zc row at (b,y),
// x-window W=16; pinned 28-plane burst; per-x LDS row staging for Z;
// lgkmcnt-only barrier (no vmcnt drain).
template <int W, bool DOZ>
__global__ __launch_bounds__(256, 1) void xzconv(const float* __restrict__ src,
                                                 float* __restrict__ dst,
                                                 Taps tp) {
    __shared__ float row[2][ZC];

    const int t   = threadIdx.x;
    const int gid = blockIdx.x;
    const int y   = (Y_ - 1) - (gid & (Y_ - 1));   // reversed: hit last-written tmp
    const int xw  = (gid >> 7) & (X_ / W - 1);
    const int b   = gid >> 10;

    const int x0   = xw * W;
    const int base = b * BS + y * ZC + (t << 2);   // this thread's f4 at plane x=0
    const int z    = t >> 1;
    const int cw   = (t & 1) << 2;

    float4 v[W + 2 * TAIL];
#pragma unroll
    for (int i = 0; i < W + 2 * TAIL; ++i) {
        const int xx = x0 - TAIL + i;
        v[i] = (xx >= 0 && xx < X_) ? ld4(src + base + xx * XS) : f4zero();
    }
#pragma unroll
    for (int i = 0; i < W + 2 * TAIL; ++i) {
        asm volatile("" : "+v"(v[i].x), "+v"(v[i].y), "+v"(v[i].z), "+v"(v[i].w));
    }
    __builtin_amdgcn_sched_barrier(0);

    int pp = 0;
#pragma unroll
    for (int j = 0; j < W; ++j) {
        float4 acc = f4zero();
#pragma unroll
        for (int i = 0; i < KTAPS; ++i) fma4(acc, tp.k[i], v[j + i]);

        if (DOZ) {
            st4(&row[pp][t << 2], acc);
            asm volatile("s_waitcnt lgkmcnt(0)" ::: "memory");
            __builtin_amdgcn_s_barrier();
            __builtin_amdgcn_sched_barrier(0);

            float4 zacc = f4zero();
#pragma unroll
            for (int i = 0; i < KTAPS; ++i) {
                const int zz = z - TAIL + i;
                if (zz >= 0 && zz < Z_) {
                    fma4(zacc, tp.k[i], ld4(&row[pp][(zz << 3) + cw]));
                }
            }
            st4(dst + base + (x0 + j) * XS, zacc);
            pp ^= 1;
        } else {
            st4(dst + base + (x0 + j) * XS, acc);
        }
    }
}

// -------- Fallback-only: fused Y+Z, single plane per block, in-place-safe ----
template <int SEGY, int P>
__global__ __launch_bounds__(256) void yzconv_kernel(const float* __restrict__ src,
                                                     float* __restrict__ dst,
                                                     Taps tp) {
    __shared__ float row[2][ZC];

    const int t    = threadIdx.x;
    const int s    = blockIdx.x % SEGY;
    const int rest = blockIdx.x / SEGY;
    const int x    = rest & (X_ - 1);
    const int b    = rest >> 7;

    const int pbase = b * BS + x * XS;
    const int zc    = t << 2;
    const int z     = t >> 1;
    const int cw    = (t & 1) << 2;

    const int ylen = Y_ / SEGY;
    const int y0   = s * ylen;

    auto ldrow = [&](int yy) -> float4 {
        return (yy >= 0 && yy < Y_) ? ld4(src + pbase + yy * ZC + zc) : f4zero();
    };

    float4 w[KTAPS];
#pragma unroll
    for (int i = 0; i < KTAPS - 1; ++i) w[i] = ldrow(y0 - TAIL + i);
    float4 pf[P];
#pragma unroll
    for (int i = 0; i < P; ++i) pf[i] = ldrow(y0 + TAIL + i);

    int p = 0;
    for (int yy = 0; yy < ylen; yy += P) {
#pragma unroll
        for (int k = 0; k < P; ++k) {
            const int y = y0 + yy + k;
            w[KTAPS - 1] = pf[k];
            pf[k] = ldrow(y + TAIL + P);

            float4 acc = f4zero();
#pragma unroll
            for (int i = 0; i < KTAPS; ++i) fma4(acc, tp.k[i], w[i]);
            st4(&row[p][zc], acc);
            asm volatile("s_waitcnt lgkmcnt(0)" ::: "memory");
            __builtin_amdgcn_s_barrier();
            __builtin_amdgcn_sched_barrier(0);

            float4 zacc = f4zero();
#pragma unroll
            for (int i = 0; i < KTAPS; ++i) {
                const int zz = z - TAIL + i;
                if (zz >= 0 && zz < Z_) {
                    fma4(zacc, tp.k[i], ld4(&row[p][(zz << 3) + cw]));
                }
            }
            st4(dst + pbase + y * ZC + zc, zacc);

#pragma unroll
            for (int i = 0; i < KTAPS - 1; ++i) w[i] = w[i + 1];
            p ^= 1;
        }
    }
}

extern "C" void kernel_launch(void* const* d_in, const int* in_sizes, int n_in,
                              void* d_out, int out_size, void* d_ws, size_t ws_size,
                              hipStream_t stream) {
    const float* in = (const float*)d_in[0];
    float* out = (float*)d_out;

    // Gaussian taps: tail = int(2.0*3.0 + 0.5) = 6, K = 13, sigma = 2
    Taps tp;
    {
        float kv[KTAPS];
        float sum = 0.f;
        for (int i = 0; i < KTAPS; ++i) {
            const float xx = (float)(i - TAIL);
            kv[i] = expf(-0.5f * xx * xx / 4.0f);
            sum += kv[i];
        }
        for (int i = 0; i < KTAPS; ++i) tp.k[i] = kv[i] / sum;
    }

    const size_t need_bytes = (size_t)B_ * BS * sizeof(float);  // 134 MB
    const bool use_ws = (ws_size >= need_bytes) && (d_ws != nullptr);
    float* tmp = use_ws ? (float*)d_ws : out;

    if (use_ws) {
        // Pass 1: XCD-chunked compact-band Y conv, in (cold) -> tmp.
        // 2048 chunks of T=16 rows; each XCD owns a contiguous 256-chunk run.
        ygather<16><<<2048, 256, 0, stream>>>(in, tmp, tp);
        // Pass 2: X gather (tmp L3-warm) + Z via LDS -> out. 2048 blocks.
        xzconv<16, true><<<B_ * (X_ / 16) * Y_, 256, 0, stream>>>(tmp, out, tp);
    } else {
        // Fallback (never expected): X-only gather in->out, then in-place
        // fused Y+Z per plane (block-local, writes trail reads).
        xzconv<16, false><<<B_ * (X_ / 16) * Y_, 256, 0, stream>>>(in, out, tp);
        yzconv_kernel<1, 4><<<B_ * X_, 256, 0, stream>>>(out, out, tp);
    }
}

// Round 13
// 114.552 us; speedup vs baseline: 1.1897x; 1.0321x over previous
//
#include <hip/hip_runtime.h>
#include <cmath>

#define B_ 2
#define X_ 128
#define Y_ 128
#define Z_ 128
#define C_ 8
#define ZC 1024         // Z_*C_ floats per row
#define XS 131072       // Y_*ZC, stride of x in elements
#define BS 16777216     // X_*XS, stride of batch in elements
#define KTAPS 13
#define TAIL 6

struct Taps { float k[KTAPS]; };

__device__ __forceinline__ float4 ld4(const float* p) {
    return *reinterpret_cast<const float4*>(p);
}
__device__ __forceinline__ void st4(float* p, const float4& v) {
    *reinterpret_cast<float4*>(p) = v;
}
__device__ __forceinline__ float4 f4zero() { return make_float4(0.f, 0.f, 0.f, 0.f); }
__device__ __forceinline__ void fma4(float4& a, float s, const float4& b) {
    a.x = fmaf(s, b.x, a.x); a.y = fmaf(s, b.y, a.y);
    a.z = fmaf(s, b.z, a.z); a.w = fmaf(s, b.w, a.w);
}

typedef __attribute__((address_space(3))) unsigned int lds_u32;
typedef const __attribute__((address_space(1))) unsigned int glb_u32;

// ---------------- Pass 1: Y conv via global_load_lds DMA staging -------------
// R1-R12 model: cold reads through the vector-L1 path cap at ~2.8 TB/s
// chip-wide (per-CU outstanding-line limit x 256 CU / ~900cy HBM latency);
// warm reads ~12 TB/s, writes ~7 TB/s -- confirmed by every round. This pass
// routes the cold read around that path: global_load_lds (DMA direct-to-LDS,
// the cp.async analog) stages 20 contiguous 4KB y-rows; wave w DMAs byte
// quarter [w*1KB] of every row. Thread t consumes only column t*16B, which
// lies in its own wave's quarter -> NO s_barrier, just vmcnt(0) per wave.
// Compute: rolling 13-row register window fed by ds_read_b128 (conflict-free
// 16B/lane contiguous). LDS 80KB -> 2 blocks/CU: block A's DMA overlaps
// block B's compute. Grid is XCD-chunked (R12: FETCH 158->77 MB).
template <int T>
__global__ __launch_bounds__(256) void ydma(const float* __restrict__ src,
                                            float* __restrict__ dst,
                                            Taps tp) {
    __shared__ float lds[(T + 2 * TAIL) * ZC];

    const int t = threadIdx.x;
    const int w = t >> 6;                           // wave 0..3
    const int l = t & 63;

    // 4096 chunks; bijective XCD-chunked map: each XCD owns 512 consecutive.
    const int g  = (blockIdx.x & 7) * 512 + (blockIdx.x >> 3);
    const int p  = g >> 4;                          // plane index (Y_/T = 16)
    const int y0 = (g & 15) * T;

    const float* sp = src + (size_t)p * XS;
    float*       dp = dst + (size_t)p * XS + (t << 2);

    // Zero-fill OOB rows (each thread its own 16B slot; lgkmcnt covers it).
#pragma unroll
    for (int i = 0; i < T + 2 * TAIL; ++i) {
        const int yy = y0 - TAIL + i;
        if (yy < 0 || yy >= Y_) {
            st4(&lds[i * ZC + (t << 2)], f4zero());
        }
    }

    // DMA: wave w stages bytes [w*1024, w*1024+1024) of each valid row.
    // LDS dest is wave-uniform base; HW adds lane*16.
#pragma unroll
    for (int i = 0; i < T + 2 * TAIL; ++i) {
        const int yy = y0 - TAIL + i;
        if (yy >= 0 && yy < Y_) {
            const float* g4 = sp + (size_t)yy * ZC + (w << 8) + (l << 2);
            __builtin_amdgcn_global_load_lds((glb_u32*)g4,
                                             (lds_u32*)&lds[i * ZC + (w << 8)],
                                             16, 0, 0);
        }
    }
    asm volatile("s_waitcnt vmcnt(0) lgkmcnt(0)" ::: "memory");
    __builtin_amdgcn_sched_barrier(0);
    // No s_barrier: wave w reads only columns inside its own DMA'd quarter.

    // Rolling 13-row window from LDS.
    float4 win[KTAPS - 1];
#pragma unroll
    for (int i = 0; i < KTAPS - 1; ++i) win[i] = ld4(&lds[i * ZC + (t << 2)]);

#pragma unroll
    for (int j = 0; j < T; ++j) {
        const float4 cur = ld4(&lds[(j + KTAPS - 1) * ZC + (t << 2)]);
        float4 acc = f4zero();
#pragma unroll
        for (int i = 0; i < KTAPS - 1; ++i) fma4(acc, tp.k[i], win[i]);
        fma4(acc, tp.k[KTAPS - 1], cur);
        st4(dp + (size_t)(y0 + j) * ZC, acc);
#pragma unroll
        for (int i = 0; i < KTAPS - 2; ++i) win[i] = win[i + 1];
        win[KTAPS - 2] = cur;
    }
}

// ------------- Pass 2: X-conv gather (L3-warm) + Z-conv via LDS row ----------
// Measured 33-38us on warm tmp (R8/R10/R12). Block = one zc row at (b,y),
// x-window W=16; pinned 28-plane burst; per-x LDS row staging for Z;
// lgkmcnt-only barrier (no vmcnt drain).
template <int W, bool DOZ>
__global__ __launch_bounds__(256, 1) void xzconv(const float* __restrict__ src,
                                                 float* __restrict__ dst,
                                                 Taps tp) {
    __shared__ float row[2][ZC];

    const int t   = threadIdx.x;
    const int gid = blockIdx.x;
    const int y   = (Y_ - 1) - (gid & (Y_ - 1));   // reversed: hit last-written tmp
    const int xw  = (gid >> 7) & (X_ / W - 1);
    const int b   = gid >> 10;

    const int x0   = xw * W;
    const int base = b * BS + y * ZC + (t << 2);   // this thread's f4 at plane x=0
    const int z    = t >> 1;
    const int cw   = (t & 1) << 2;

    float4 v[W + 2 * TAIL];
#pragma unroll
    for (int i = 0; i < W + 2 * TAIL; ++i) {
        const int xx = x0 - TAIL + i;
        v[i] = (xx >= 0 && xx < X_) ? ld4(src + base + xx * XS) : f4zero();
    }
#pragma unroll
    for (int i = 0; i < W + 2 * TAIL; ++i) {
        asm volatile("" : "+v"(v[i].x), "+v"(v[i].y), "+v"(v[i].z), "+v"(v[i].w));
    }
    __builtin_amdgcn_sched_barrier(0);

    int pp = 0;
#pragma unroll
    for (int j = 0; j < W; ++j) {
        float4 acc = f4zero();
#pragma unroll
        for (int i = 0; i < KTAPS; ++i) fma4(acc, tp.k[i], v[j + i]);

        if (DOZ) {
            st4(&row[pp][t << 2], acc);
            asm volatile("s_waitcnt lgkmcnt(0)" ::: "memory");
            __builtin_amdgcn_s_barrier();
            __builtin_amdgcn_sched_barrier(0);

            float4 zacc = f4zero();
#pragma unroll
            for (int i = 0; i < KTAPS; ++i) {
                const int zz = z - TAIL + i;
                if (zz >= 0 && zz < Z_) {
                    fma4(zacc, tp.k[i], ld4(&row[pp][(zz << 3) + cw]));
                }
            }
            st4(dst + base + (x0 + j) * XS, zacc);
            pp ^= 1;
        } else {
            st4(dst + base + (x0 + j) * XS, acc);
        }
    }
}

// -------- Fallback-only: fused Y+Z, single plane per block, in-place-safe ----
template <int SEGY, int P>
__global__ __launch_bounds__(256) void yzconv_kernel(const float* __restrict__ src,
                                                     float* __restrict__ dst,
                                                     Taps tp) {
    __shared__ float row[2][ZC];

    const int t    = threadIdx.x;
    const int s    = blockIdx.x % SEGY;
    const int rest = blockIdx.x / SEGY;
    const int x    = rest & (X_ - 1);
    const int b    = rest >> 7;

    const int pbase = b * BS + x * XS;
    const int zc    = t << 2;
    const int z     = t >> 1;
    const int cw    = (t & 1) << 2;

    const int ylen = Y_ / SEGY;
    const int y0   = s * ylen;

    auto ldrow = [&](int yy) -> float4 {
        return (yy >= 0 && yy < Y_) ? ld4(src + pbase + yy * ZC + zc) : f4zero();
    };

    float4 w[KTAPS];
#pragma unroll
    for (int i = 0; i < KTAPS - 1; ++i) w[i] = ldrow(y0 - TAIL + i);
    float4 pf[P];
#pragma unroll
    for (int i = 0; i < P; ++i) pf[i] = ldrow(y0 + TAIL + i);

    int p = 0;
    for (int yy = 0; yy < ylen; yy += P) {
#pragma unroll
        for (int k = 0; k < P; ++k) {
            const int y = y0 + yy + k;
            w[KTAPS - 1] = pf[k];
            pf[k] = ldrow(y + TAIL + P);

            float4 acc = f4zero();
#pragma unroll
            for (int i = 0; i < KTAPS; ++i) fma4(acc, tp.k[i], w[i]);
            st4(&row[p][zc], acc);
            asm volatile("s_waitcnt lgkmcnt(0)" ::: "memory");
            __builtin_amdgcn_s_barrier();
            __builtin_amdgcn_sched_barrier(0);

            float4 zacc = f4zero();
#pragma unroll
            for (int i = 0; i < KTAPS; ++i) {
                const int zz = z - TAIL + i;
                if (zz >= 0 && zz < Z_) {
                    fma4(zacc, tp.k[i], ld4(&row[p][(zz << 3) + cw]));
                }
            }
            st4(dst + pbase + y * ZC + zc, zacc);

#pragma unroll
            for (int i = 0; i < KTAPS - 1; ++i) w[i] = w[i + 1];
            p ^= 1;
        }
    }
}

extern "C" void kernel_launch(void* const* d_in, const int* in_sizes, int n_in,
                              void* d_out, int out_size, void* d_ws, size_t ws_size,
                              hipStream_t stream) {
    const float* in = (const float*)d_in[0];
    float* out = (float*)d_out;

    // Gaussian taps: tail = int(2.0*3.0 + 0.5) = 6, K = 13, sigma = 2
    Taps tp;
    {
        float kv[KTAPS];
        float sum = 0.f;
        for (int i = 0; i < KTAPS; ++i) {
            const float xx = (float)(i - TAIL);
            kv[i] = expf(-0.5f * xx * xx / 4.0f);
            sum += kv[i];
        }
        for (int i = 0; i < KTAPS; ++i) tp.k[i] = kv[i] / sum;
    }

    const size_t need_bytes = (size_t)B_ * BS * sizeof(float);  // 134 MB
    const bool use_ws = (ws_size >= need_bytes) && (d_ws != nullptr);
    float* tmp = use_ws ? (float*)d_ws : out;

    if (use_ws) {
        // Pass 1: DMA-staged Y conv, in (cold) -> tmp. 4096 chunks of T=8
        // rows; 80KB LDS -> 2 blocks/CU; XCD-chunked compact bands.
        ydma<8><<<4096, 256, 0, stream>>>(in, tmp, tp);
        // Pass 2: X gather (tmp L3-warm) + Z via LDS -> out. 2048 blocks.
        xzconv<16, true><<<B_ * (X_ / 16) * Y_, 256, 0, stream>>>(tmp, out, tp);
    } else {
        // Fallback (never expected): X-only gather in->out, then in-place
        // fused Y+Z per plane (block-local, writes trail reads).
        xzconv<16, false><<<B_ * (X_ / 16) * Y_, 256, 0, stream>>>(in, out, tp);
        yzconv_kernel<1, 4><<<B_ * X_, 256, 0, stream>>>(out, out, tp);
    }
}

// Round 14
// 93.225 us; speedup vs baseline: 1.4619x; 1.2288x over previous
//
#include <hip/hip_runtime.h>
#include <hip/hip_fp16.h>
#include <cmath>

#define B_ 2
#define X_ 128
#define Y_ 128
#define Z_ 128
#define C_ 8
#define ZC 1024         // Z_*C_ elements per (x,y) row
#define XS 131072       // Y_*ZC, stride of x in elements
#define BS 16777216     // X_*XS, stride of batch in elements
#define KTAPS 13
#define TAIL 6

struct Taps { float k[KTAPS]; };

__device__ __forceinline__ float4 ld4(const float* p) {
    return *reinterpret_cast<const float4*>(p);
}
__device__ __forceinline__ void st4(float* p, const float4& v) {
    *reinterpret_cast<float4*>(p) = v;
}
__device__ __forceinline__ float4 f4zero() { return make_float4(0.f, 0.f, 0.f, 0.f); }
__device__ __forceinline__ void fma4(float4& a, float s, const float4& b) {
    a.x = fmaf(s, b.x, a.x); a.y = fmaf(s, b.y, a.y);
    a.z = fmaf(s, b.z, a.z); a.w = fmaf(s, b.w, a.w);
}
// fp16 quad pack/unpack (8B vectors)
__device__ __forceinline__ void sth4(__half* p, const float4& v) {
    __half2 lo = __floats2half2_rn(v.x, v.y);
    __half2 hi = __floats2half2_rn(v.z, v.w);
    uint2 u;
    u.x = *reinterpret_cast<unsigned int*>(&lo);
    u.y = *reinterpret_cast<unsigned int*>(&hi);
    *reinterpret_cast<uint2*>(p) = u;
}
__device__ __forceinline__ float4 h4f(uint2 u) {
    __half2 lo = *reinterpret_cast<__half2*>(&u.x);
    __half2 hi = *reinterpret_cast<__half2*>(&u.y);
    float2 a = __half22float2(lo);
    float2 b = __half22float2(hi);
    return make_float4(a.x, a.y, b.x, b.y);
}

typedef __attribute__((address_space(3))) unsigned int lds_u32;
typedef const __attribute__((address_space(1))) unsigned int glb_u32;

// ---------------- Pass 1: Y conv, DMA-staged, fp16 output --------------------
// R1-R13: cold-read delivery is capped ~1.7 TB/s/direction no matter the
// mechanism (occupancy/MLP/granularity/stream/band/DMA all tried). So shrink
// bytes: the intermediate is fp16 (err ~1e-3 << 5.6e-3 threshold). DMA stages
// 20 fp32 y-rows to LDS (wave-quarter ownership -> no s_barrier, vmcnt only);
// rolling 13-row window; fp16 8B stores halve the write stream.
template <int T>
__global__ __launch_bounds__(256) void ydma(const float* __restrict__ src,
                                            __half* __restrict__ dst,
                                            Taps tp) {
    __shared__ float lds[(T + 2 * TAIL) * ZC];

    const int t = threadIdx.x;
    const int w = t >> 6;                           // wave 0..3
    const int l = t & 63;

    // 4096 chunks; XCD-chunked bijective map (each XCD: 512 consecutive).
    const int g  = (blockIdx.x & 7) * 512 + (blockIdx.x >> 3);
    const int p  = g >> 4;                          // plane index (Y_/T = 16)
    const int y0 = (g & 15) * T;

    const float* sp = src + (size_t)p * XS;
    __half*      dp = dst + (size_t)p * XS + (t << 2);

    // Zero-fill OOB rows (own 16B slot; covered by the lgkmcnt wait below).
#pragma unroll
    for (int i = 0; i < T + 2 * TAIL; ++i) {
        const int yy = y0 - TAIL + i;
        if (yy < 0 || yy >= Y_) st4(&lds[i * ZC + (t << 2)], f4zero());
    }

    // DMA: wave w stages bytes [w*1KB, (w+1)*1KB) of each valid row.
#pragma unroll
    for (int i = 0; i < T + 2 * TAIL; ++i) {
        const int yy = y0 - TAIL + i;
        if (yy >= 0 && yy < Y_) {
            const float* g4 = sp + (size_t)yy * ZC + (w << 8) + (l << 2);
            __builtin_amdgcn_global_load_lds((glb_u32*)g4,
                                             (lds_u32*)&lds[i * ZC + (w << 8)],
                                             16, 0, 0);
        }
    }
    asm volatile("s_waitcnt vmcnt(0) lgkmcnt(0)" ::: "memory");
    __builtin_amdgcn_sched_barrier(0);
    // No s_barrier: wave w reads only columns inside its own DMA'd quarter.

    float4 win[KTAPS - 1];
#pragma unroll
    for (int i = 0; i < KTAPS - 1; ++i) win[i] = ld4(&lds[i * ZC + (t << 2)]);

#pragma unroll
    for (int j = 0; j < T; ++j) {
        const float4 cur = ld4(&lds[(j + KTAPS - 1) * ZC + (t << 2)]);
        float4 acc = f4zero();
#pragma unroll
        for (int i = 0; i < KTAPS - 1; ++i) fma4(acc, tp.k[i], win[i]);
        fma4(acc, tp.k[KTAPS - 1], cur);
        sth4(dp + (size_t)(y0 + j) * ZC, acc);
#pragma unroll
        for (int i = 0; i < KTAPS - 2; ++i) win[i] = win[i + 1];
        win[KTAPS - 2] = cur;
    }
}

// ------------- Pass 2: X-conv gather (fp16 L3-warm) + Z-conv via LDS ---------
// Block = one zc row at (b,y), x-window W=16; pinned 28-plane 8B-load burst
// (fp16 tmp = 67MB, fully L3-resident); per-x LDS row staging for Z-conv;
// lgkmcnt-only barrier (no vmcnt drain). Output fp32.
template <int W, bool HSRC, bool DOZ>
__global__ __launch_bounds__(256, 1) void xzconv(const void* __restrict__ srcv,
                                                 float* __restrict__ dst,
                                                 Taps tp) {
    __shared__ float row[2][ZC];

    const int t   = threadIdx.x;
    const int gid = blockIdx.x;
    const int y   = (Y_ - 1) - (gid & (Y_ - 1));   // reversed: hit last-written tmp
    const int xw  = (gid >> 7) & (X_ / W - 1);
    const int b   = gid >> 10;

    const int x0   = xw * W;
    const size_t base = (size_t)b * BS + (size_t)y * ZC + (t << 2);
    const int z    = t >> 1;
    const int cw   = (t & 1) << 2;

    float4 v[W + 2 * TAIL];
    if (HSRC) {
        const __half* src = (const __half*)srcv;
        uint2 raw[W + 2 * TAIL];
#pragma unroll
        for (int i = 0; i < W + 2 * TAIL; ++i) {
            const int xx = x0 - TAIL + i;
            raw[i] = (xx >= 0 && xx < X_)
                   ? *reinterpret_cast<const uint2*>(src + base + (size_t)xx * XS)
                   : make_uint2(0u, 0u);
        }
#pragma unroll
        for (int i = 0; i < W + 2 * TAIL; ++i) {
            asm volatile("" : "+v"(raw[i].x), "+v"(raw[i].y));
        }
        __builtin_amdgcn_sched_barrier(0);
#pragma unroll
        for (int i = 0; i < W + 2 * TAIL; ++i) v[i] = h4f(raw[i]);
    } else {
        const float* src = (const float*)srcv;
#pragma unroll
        for (int i = 0; i < W + 2 * TAIL; ++i) {
            const int xx = x0 - TAIL + i;
            v[i] = (xx >= 0 && xx < X_) ? ld4(src + base + (size_t)xx * XS) : f4zero();
        }
#pragma unroll
        for (int i = 0; i < W + 2 * TAIL; ++i) {
            asm volatile("" : "+v"(v[i].x), "+v"(v[i].y), "+v"(v[i].z), "+v"(v[i].w));
        }
        __builtin_amdgcn_sched_barrier(0);
    }

    int pp = 0;
#pragma unroll
    for (int j = 0; j < W; ++j) {
        float4 acc = f4zero();
#pragma unroll
        for (int i = 0; i < KTAPS; ++i) fma4(acc, tp.k[i], v[j + i]);

        if (DOZ) {
            st4(&row[pp][t << 2], acc);
            asm volatile("s_waitcnt lgkmcnt(0)" ::: "memory");
            __builtin_amdgcn_s_barrier();
            __builtin_amdgcn_sched_barrier(0);

            float4 zacc = f4zero();
#pragma unroll
            for (int i = 0; i < KTAPS; ++i) {
                const int zz = z - TAIL + i;
                if (zz >= 0 && zz < Z_) {
                    fma4(zacc, tp.k[i], ld4(&row[pp][(zz << 3) + cw]));
                }
            }
            st4(dst + base + (size_t)(x0 + j) * XS, zacc);
            pp ^= 1;
        } else {
            st4(dst + base + (size_t)(x0 + j) * XS, acc);
        }
    }
}

// -------- Fallback-only: fused Y+Z, single plane per block, in-place-safe ----
template <int SEGY, int P>
__global__ __launch_bounds__(256) void yzconv_kernel(const float* __restrict__ src,
                                                     float* __restrict__ dst,
                                                     Taps tp) {
    __shared__ float row[2][ZC];

    const int t    = threadIdx.x;
    const int s    = blockIdx.x % SEGY;
    const int rest = blockIdx.x / SEGY;
    const int x    = rest & (X_ - 1);
    const int b    = rest >> 7;

    const int pbase = b * BS + x * XS;
    const int zc    = t << 2;
    const int z     = t >> 1;
    const int cw    = (t & 1) << 2;

    const int ylen = Y_ / SEGY;
    const int y0   = s * ylen;

    auto ldrow = [&](int yy) -> float4 {
        return (yy >= 0 && yy < Y_) ? ld4(src + pbase + yy * ZC + zc) : f4zero();
    };

    float4 w[KTAPS];
#pragma unroll
    for (int i = 0; i < KTAPS - 1; ++i) w[i] = ldrow(y0 - TAIL + i);
    float4 pf[P];
#pragma unroll
    for (int i = 0; i < P; ++i) pf[i] = ldrow(y0 + TAIL + i);

    int p = 0;
    for (int yy = 0; yy < ylen; yy += P) {
#pragma unroll
        for (int k = 0; k < P; ++k) {
            const int y = y0 + yy + k;
            w[KTAPS - 1] = pf[k];
            pf[k] = ldrow(y + TAIL + P);

            float4 acc = f4zero();
#pragma unroll
            for (int i = 0; i < KTAPS; ++i) fma4(acc, tp.k[i], w[i]);
            st4(&row[p][zc], acc);
            asm volatile("s_waitcnt lgkmcnt(0)" ::: "memory");
            __builtin_amdgcn_s_barrier();
            __builtin_amdgcn_sched_barrier(0);

            float4 zacc = f4zero();
#pragma unroll
            for (int i = 0; i < KTAPS; ++i) {
                const int zz = z - TAIL + i;
                if (zz >= 0 && zz < Z_) {
                    fma4(zacc, tp.k[i], ld4(&row[p][(zz << 3) + cw]));
                }
            }
            st4(dst + pbase + y * ZC + zc, zacc);

#pragma unroll
            for (int i = 0; i < KTAPS - 1; ++i) w[i] = w[i + 1];
            p ^= 1;
        }
    }
}

extern "C" void kernel_launch(void* const* d_in, const int* in_sizes, int n_in,
                              void* d_out, int out_size, void* d_ws, size_t ws_size,
                              hipStream_t stream) {
    const float* in = (const float*)d_in[0];
    float* out = (float*)d_out;

    // Gaussian taps: tail = int(2.0*3.0 + 0.5) = 6, K = 13, sigma = 2
    Taps tp;
    {
        float kv[KTAPS];
        float sum = 0.f;
        for (int i = 0; i < KTAPS; ++i) {
            const float xx = (float)(i - TAIL);
            kv[i] = expf(-0.5f * xx * xx / 4.0f);
            sum += kv[i];
        }
        for (int i = 0; i < KTAPS; ++i) tp.k[i] = kv[i] / sum;
    }

    const size_t need_bytes = (size_t)B_ * BS * sizeof(__half);  // 67 MB
    const bool use_ws = (ws_size >= need_bytes) && (d_ws != nullptr);

    if (use_ws) {
        __half* tmp = (__half*)d_ws;
        // Pass 1: DMA-staged Y conv, in (cold, fp32) -> tmp (fp16).
        ydma<8><<<4096, 256, 0, stream>>>(in, tmp, tp);
        // Pass 2: X gather (fp16 tmp, L3-resident) + Z via LDS -> out (fp32).
        xzconv<16, true, true><<<B_ * (X_ / 16) * Y_, 256, 0, stream>>>(tmp, out, tp);
    } else {
        // Fallback: fp32 X-only gather in->out, then in-place fused Y+Z.
        xzconv<16, false, false><<<B_ * (X_ / 16) * Y_, 256, 0, stream>>>(in, out, tp);
        yzconv_kernel<1, 4><<<B_ * X_, 256, 0, stream>>>(out, out, tp);
    }
}